// Round 12
// baseline (432.571 us; speedup 1.0000x reference)
//
#include <hip/hip_runtime.h>
#include <hip/hip_cooperative_groups.h>

namespace cg = cooperative_groups;

// HGCN on MI355X. logmap0(expmap0(v)) == v here, so the model reduces to:
//   t1 = sigmoid(segmean(feat@W1+b1)); t2 = sigmoid(segmean(t1@W2+b2))
//   out = relu(t2@W3+b3)@W4 + b4     (segmean commutes with the linear map;
//   deg-0 nodes: segmean = 0 -> value 0.5 exactly, handled via dz check)
// R1-R13: see session journal. R14: re-anchor 229.4us.
// R15/R16: FAILED. R17: WIN (219). R18: partial. R19: NULL. R20: NULL.
// R21: 211.7 BEST (CSHIFT=8 split prep; gathers 128thr/32row @ 48us).
// R22: FAILED (367; 4B scatter write-amp). R23: FAILED (1315; LDS atomic
//   THROUGHPUT ~3.6cyc/lane-op is a HW wall -- encoding irrelevant).
// R24: NULL (216.7; co-residency + chunk order: FETCH still 82MB).
//   GATHER DECLARED ROOFLINED: 5 independent attacks leave it at ~48us,
//   ~2TB/s random-fabric, FETCH ~80MB. Not touched from here on.
// R25: prep STRUCTURE round. One cooperative kernel (391 blocks x 512thr,
//   34KB LDS, fully co-resident) replaces memset+part_prep+csr_fine:
//   ph0 zero ccur | sync | ph1 partition + grid-stride cast/img (BW filler
//   absorbs partition stragglers) | sync | ph2 per-bucket counting sort.
//   Dispatches 5 -> 3; csr_fine no longer waits on cast. Gathers/GEMMs =
//   R21 bit-for-bit. Pre-commit: prep_all > 85us => revert to split.
//   Predicted total 211.7 -> ~180-195.

constexpr int CSHIFT = 8;               // 256 nodes per coarse bucket
constexpr int CNODES = 1 << CSHIFT;
constexpr int EPB    = 4096;            // edges per partition block
constexpr int PTHR   = 512;             // prep block threads
constexpr int EPT    = EPB / PTHR;      // 8 edges/thread
constexpr int CAP    = 6144;            // arena cap/bucket (mean 4082)

// frag-packed bf16 weight image (shorts). Fragment = 16 lanes x 8 shorts =
// 128 shorts; flat idx = (((c*KK + kk)*4 + quad)*16 + m)*8 + j.
constexpr int W1F_OFF = 0;              // 4x2x4 frags  = 4096 shorts
constexpr int W2F_OFF = 4096;           // 4096
constexpr int W3F_OFF = 8192;           // 8x2x4 frags  = 8192
constexpr int W4F_OFF = 16384;          // 3x4x4 frags  = 6144 (cols padded 48)
constexpr int WIMG_TOT = 22528;

typedef __attribute__((ext_vector_type(8))) short short8;   // 8 bf16
typedef __attribute__((ext_vector_type(4))) float floatx4;  // MFMA acc

__device__ __forceinline__ float sigmoidf(float x) {
    return 1.0f / (1.0f + __expf(-x));
}
__device__ __forceinline__ unsigned short f2bf(float f) {   // RNE f32->bf16
    unsigned int u = __float_as_uint(f);
    u = (u + 0x7FFFu + ((u >> 16) & 1u)) >> 16;
    return (unsigned short)u;
}

// ---------------- cooperative prep: partition + cast/img + sort ------------
// 391 blocks x 512 threads, fully co-resident (34KB LDS -> 4 blocks/CU cap,
// 8 waves/block x 391 = 3128 waves < 8192 capacity).
__global__ __launch_bounds__(PTHR) void prep_all_k(
    const int* __restrict__ src, const int* __restrict__ dst,
    int* __restrict__ ccur, int* __restrict__ arena,
    int* __restrict__ off, int* __restrict__ ssrc,
    int E, int N, int NBUCK, int gP,
    const float* __restrict__ feat, unsigned short* __restrict__ featbf,
    const float* __restrict__ W1, const float* __restrict__ W2,
    const float* __restrict__ W3, const float* __restrict__ W4,
    unsigned short* __restrict__ img, int n8)
{
    cg::grid_group grid = cg::this_grid();

    __shared__ int  hist[512];
    __shared__ int  exoff[512];
    __shared__ int  lcur[512];
    __shared__ int  gbase[512];
    __shared__ int  wsum[8];
    __shared__ int  stage[EPB];              // 16 KB
    __shared__ unsigned short stageS[EPB];   // 8 KB
    __shared__ int  cnt[CNODES];
    __shared__ int  cur[CNODES];
    __shared__ int  wpre2[4];
    __shared__ int  cbeg_s;

    const int tid = threadIdx.x;
    const int bid = blockIdx.x;
    const int lane = tid & 63, wid = tid >> 6;

    // ---- phase 0: zero ccur (replaces memset dispatch) ----
    if (bid == 0 && tid < NBUCK) ccur[tid] = 0;
    __threadfence();
    grid.sync();

    // ---- phase 1a: partition this block's EPB edges (R21 path) ----
    if (bid < gP) {
        const int e0 = bid * EPB;
        const int ec = min(EPB, E - e0);

        int pk[EPT], bk[EPT];
        hist[tid] = 0;
        __syncthreads();
        #pragma unroll
        for (int j = 0; j < EPT; j++) {
            int idx = tid + j * PTHR;
            if (idx < ec) {
                int s = src[e0 + idx];
                int d = dst[e0 + idx];
                bk[j] = d >> CSHIFT;
                pk[j] = s | ((d & (CNODES - 1)) << 17);
                atomicAdd(&hist[bk[j]], 1);
            } else bk[j] = -1;
        }
        __syncthreads();
        int h = hist[tid];
        int v = h;
        #pragma unroll
        for (int d = 1; d < 64; d <<= 1) {
            int t = __shfl_up(v, d);
            if (lane >= d) v += t;
        }
        if (lane == 63) wsum[wid] = v;
        __syncthreads();
        if (tid == 0) {
            int s = 0;
            #pragma unroll
            for (int k = 0; k < 8; k++) { int t = wsum[k]; wsum[k] = s; s += t; }
        }
        __syncthreads();
        {
            int ex = wsum[wid] + v - h;
            int gb = 0;
            if (tid < NBUCK && h > 0) gb = atomicAdd(ccur + tid, h);
            exoff[tid] = ex;
            lcur[tid]  = ex;
            gbase[tid] = gb;
        }
        __syncthreads();
        #pragma unroll
        for (int j = 0; j < EPT; j++) {
            if (bk[j] >= 0) {
                int l = atomicAdd(&lcur[bk[j]], 1);
                stage[l]  = pk[j];
                stageS[l] = (unsigned short)bk[j];
            }
        }
        __syncthreads();
        for (int i = tid; i < ec; i += PTHR) {
            int b = stageS[i];
            arena[(size_t)b * CAP + gbase[b] + (i - exoff[b])] = stage[i];
        }
    }

    // ---- phase 1b: grid-stride cast + img (BW filler, no dependency) ----
    {
        const int nW = n8 + WIMG_TOT;
        for (int i = bid * PTHR + tid; i < nW; i += gridDim.x * PTHR) {
            if (i < n8) {
                const float4* p = (const float4*)feat + (size_t)i * 2;
                float4 a = p[0], b = p[1];
                uint4 o;
                o.x = (unsigned)f2bf(a.x) | ((unsigned)f2bf(a.y) << 16);
                o.y = (unsigned)f2bf(a.z) | ((unsigned)f2bf(a.w) << 16);
                o.z = (unsigned)f2bf(b.x) | ((unsigned)f2bf(b.y) << 16);
                o.w = (unsigned)f2bf(b.z) | ((unsigned)f2bf(b.w) << 16);
                ((uint4*)featbf)[i] = o;
                continue;
            }
            int t = i - n8;
            float v = 0.f;
            int s = t;
            if (s < W2F_OFF) {                       // W1 [64x64]
                int j = s & 7, m = (s >> 3) & 15, q = (s >> 7) & 3, kk = (s >> 9) & 1, c = s >> 10;
                v = W1[(kk * 32 + q * 8 + j) * 64 + c * 16 + m];
            } else if (s < W3F_OFF) {                // W2 [64x64]
                s -= W2F_OFF;
                int j = s & 7, m = (s >> 3) & 15, q = (s >> 7) & 3, kk = (s >> 9) & 1, c = s >> 10;
                v = W2[(kk * 32 + q * 8 + j) * 64 + c * 16 + m];
            } else if (s < W4F_OFF) {                // W3 [64x128]
                s -= W3F_OFF;
                int j = s & 7, m = (s >> 3) & 15, q = (s >> 7) & 3, kk = (s >> 9) & 1, c = s >> 10;
                v = W3[(kk * 32 + q * 8 + j) * 128 + c * 16 + m];
            } else {                                 // W4 [128x40], cols padded 48
                s -= W4F_OFF;
                int j = s & 7, m = (s >> 3) & 15, q = (s >> 7) & 3, kk = (s >> 9) & 3, c = s >> 11;
                int n = c * 16 + m;
                if (n < 40) v = W4[(kk * 32 + q * 8 + j) * 40 + n];
            }
            img[t] = f2bf(v);
        }
    }
    __threadfence();
    grid.sync();

    // ---- phase 2: counting sort of bucket bid (R21 csr_fine @512thr) ----
    if (bid < NBUCK) {
        // cross-bucket exclusive prefix -> cbeg (NBUCK <= 512)
        int c0 = (tid < NBUCK) ? ccur[tid] : 0;
        int v0 = c0;
        #pragma unroll
        for (int d = 1; d < 64; d <<= 1) {
            int t = __shfl_up(v0, d);
            if (lane >= d) v0 += t;
        }
        if (lane == 63) wsum[wid] = v0;
        __syncthreads();
        if (tid == 0) {
            int s = 0;
            #pragma unroll
            for (int k = 0; k < 8; k++) { int t = wsum[k]; wsum[k] = s; s += t; }
        }
        __syncthreads();
        if (tid == bid) cbeg_s = wsum[wid] + v0 - c0;   // excl prefix @ bid
        if (bid == 0 && tid == 0) off[N] = E;
        __syncthreads();
        const int cbeg = cbeg_s;
        const int ec   = min(ccur[bid], CAP);
        const int node0 = bid << CSHIFT;

        if (tid < CNODES) cnt[tid] = 0;
        __syncthreads();
        const int* pe = arena + (size_t)bid * CAP;
        for (int i = tid; i < ec; i += PTHR)
            atomicAdd(&cnt[(pe[i] >> 17) & (CNODES - 1)], 1);
        __syncthreads();

        int c = 0, v = 0;
        if (tid < CNODES) {
            c = cnt[tid];
            v = c;
            #pragma unroll
            for (int d = 1; d < 64; d <<= 1) {
                int t = __shfl_up(v, d);
                if (lane >= d) v += t;
            }
            if (lane == 63) wpre2[wid] = v;
        }
        __syncthreads();
        if (tid == 0) {
            int s = 0;
            #pragma unroll
            for (int k = 0; k < CNODES / 64; k++) { int t = wpre2[k]; wpre2[k] = s; s += t; }
        }
        __syncthreads();
        if (tid < CNODES) {
            int ex = wpre2[wid] + v - c;
            cur[tid] = ex;
            int node = node0 + tid;
            if (node < N) off[node] = cbeg + ex;
        }
        __syncthreads();
        for (int i = tid; i < ec; i += PTHR) {
            int p = pe[i];
            int pos = cbeg + atomicAdd(&cur[(p >> 17) & (CNODES - 1)], 1);
            ssrc[pos] = p & 0x1FFFF;
        }
    }
}

// ---------------- wave-local gather: mean of h[src] rows into LDS tile -----
// Wave w gathers ITS OWN rows w*16..w*16+15 (2 passes x 8 rows x 8 lanes).
// R17/R21-proven 8-deep stream loop; ROOFLINED (R24) -- do not modify.
#define ACC8(v)                                    \
    acc[0] += __uint_as_float((v).x << 16);        \
    acc[1] += __uint_as_float((v).x & 0xFFFF0000u);\
    acc[2] += __uint_as_float((v).y << 16);        \
    acc[3] += __uint_as_float((v).y & 0xFFFF0000u);\
    acc[4] += __uint_as_float((v).z << 16);        \
    acc[5] += __uint_as_float((v).z & 0xFFFF0000u);\
    acc[6] += __uint_as_float((v).w << 16);        \
    acc[7] += __uint_as_float((v).w & 0xFFFF0000u);

__device__ __forceinline__ void gather_tile_wave(
    const unsigned short* __restrict__ h, const int* __restrict__ off,
    const int* __restrict__ ssrc, unsigned short* Agg, int rowB, int N,
    int w, int lane)
{
    #pragma unroll
    for (int pass = 0; pass < 2; pass++) {
        int rl = w * 16 + pass * 8 + (lane >> 3);
        int g  = rowB + rl;
        int q  = (lane & 7) * 8;
        uint4 p = make_uint4(0u, 0u, 0u, 0u);
        if (g < N) {
            int beg = off[g], end = off[g + 1];
            float acc[8] = {0.f, 0.f, 0.f, 0.f, 0.f, 0.f, 0.f, 0.f};
            int i = beg;
            for (; i + 8 <= end; i += 8) {       // 8 loads in flight per lane
                uint4 v0 = *(const uint4*)(h + (size_t)ssrc[i]     * 64 + q);
                uint4 v1 = *(const uint4*)(h + (size_t)ssrc[i + 1] * 64 + q);
                uint4 v2 = *(const uint4*)(h + (size_t)ssrc[i + 2] * 64 + q);
                uint4 v3 = *(const uint4*)(h + (size_t)ssrc[i + 3] * 64 + q);
                uint4 v4 = *(const uint4*)(h + (size_t)ssrc[i + 4] * 64 + q);
                uint4 v5 = *(const uint4*)(h + (size_t)ssrc[i + 5] * 64 + q);
                uint4 v6 = *(const uint4*)(h + (size_t)ssrc[i + 6] * 64 + q);
                uint4 v7 = *(const uint4*)(h + (size_t)ssrc[i + 7] * 64 + q);
                ACC8(v0); ACC8(v1); ACC8(v2); ACC8(v3);
                ACC8(v4); ACC8(v5); ACC8(v6); ACC8(v7);
            }
            for (; i + 2 <= end; i += 2) {
                uint4 v0 = *(const uint4*)(h + (size_t)ssrc[i]     * 64 + q);
                uint4 v1 = *(const uint4*)(h + (size_t)ssrc[i + 1] * 64 + q);
                ACC8(v0); ACC8(v1);
            }
            for (; i < end; i++) {
                uint4 v = *(const uint4*)(h + (size_t)ssrc[i] * 64 + q);
                ACC8(v);
            }
            // v_rcp_f32: 2^-22 rel err, absorbed by the bf16 round
            float inv = __builtin_amdgcn_rcpf((float)max(end - beg, 1));
            p.x = (unsigned)f2bf(acc[0]*inv) | ((unsigned)f2bf(acc[1]*inv) << 16);
            p.y = (unsigned)f2bf(acc[2]*inv) | ((unsigned)f2bf(acc[3]*inv) << 16);
            p.z = (unsigned)f2bf(acc[4]*inv) | ((unsigned)f2bf(acc[5]*inv) << 16);
            p.w = (unsigned)f2bf(acc[6]*inv) | ((unsigned)f2bf(acc[7]*inv) << 16);
        }
        *(uint4*)(Agg + rl * 72 + q) = p;
    }
}

// ---------------- fused gather + GEMM1 + sigmoid -> t1 ---------------------
// 128 threads / 32-row tile, grid 3125 (R21 best config, unchanged).
__global__ __launch_bounds__(128) void aggemm1_k(
    const unsigned short* __restrict__ featbf, const int* __restrict__ off,
    const int* __restrict__ ssrc, const unsigned short* __restrict__ img,
    const float* __restrict__ bias, unsigned short* __restrict__ t1, int N)
{
    __shared__ alignas(16) unsigned short Agg[32 * 72];   // 4.6 KB

    const int tid = threadIdx.x;
    const int rowB = blockIdx.x * 32;
    const int w = tid >> 6, lane = tid & 63;
    const int m = lane & 15, quad = lane >> 4;
    const int row0 = rowB + w * 16;

    gather_tile_wave(featbf, off, ssrc, Agg, rowB, N, w, lane);

    const short8* Wf = (const short8*)(img + W1F_OFF);
    floatx4 acc[4];
    #pragma unroll
    for (int c = 0; c < 4; c++) acc[c] = (floatx4){0.f, 0.f, 0.f, 0.f};
    #pragma unroll
    for (int kk = 0; kk < 2; kk++) {
        short8 a = *(const short8*)(Agg + (w * 16 + m) * 72 + kk * 32 + quad * 8);
        #pragma unroll
        for (int c = 0; c < 4; c++) {
            short8 b = Wf[((c * 2 + kk) * 4 + quad) * 16 + m];
            acc[c] = __builtin_amdgcn_mfma_f32_16x16x32_bf16(a, b, acc[c], 0, 0, 0);
        }
    }
    bool dzr[4];
    int rows[4];
    #pragma unroll
    for (int r = 0; r < 4; r++) {
        rows[r] = row0 + quad * 4 + r;
        dzr[r] = (rows[r] < N) ? (off[rows[r] + 1] == off[rows[r]]) : false;
    }
    #pragma unroll
    for (int c = 0; c < 4; c++) {
        int col = c * 16 + m;
        float bv = bias[col];
        #pragma unroll
        for (int r = 0; r < 4; r++) {
            if (rows[r] < N) {
                float v = dzr[r] ? 0.5f : sigmoidf(acc[c][r] + bv);
                t1[(size_t)rows[r] * 64 + col] = f2bf(v);
            }
        }
    }
}

// ---------------- fused gather + triple-GEMM -> out ------------------------
// 128 threads / 32-row tile; LDS: T2[0,2304) | Agg/H3h[2304,4608) shorts.
// Every LDS row is touched only by its owning wave -> no __syncthreads.
__global__ __launch_bounds__(128) void aggep3_k(
    const unsigned short* __restrict__ t1, const int* __restrict__ off,
    const int* __restrict__ ssrc, const unsigned short* __restrict__ img,
    const float* __restrict__ b2, const float* __restrict__ b3,
    const float* __restrict__ b4, float* __restrict__ out, int N)
{
    __shared__ alignas(16) unsigned short SM[4608];   // 9.2 KB
    unsigned short* T2  = SM;            // 32 x 72
    unsigned short* Agg = SM + 2304;     // 32 x 72 (dead after phase 0)
    unsigned short* H3h = SM + 2304;     // aliases Agg

    const int tid = threadIdx.x;
    const int rowB = blockIdx.x * 32;
    const int w = tid >> 6, lane = tid & 63;
    const int m = lane & 15, quad = lane >> 4;
    const int row0 = rowB + w * 16;

    gather_tile_wave(t1, off, ssrc, Agg, rowB, N, w, lane);

    // ---- phase 0: T2 = sigmoid(Agg @ W2 + b2) ----
    {
        const short8* Wf = (const short8*)(img + W2F_OFF);
        floatx4 acc[4];
        #pragma unroll
        for (int c = 0; c < 4; c++) acc[c] = (floatx4){0.f, 0.f, 0.f, 0.f};
        #pragma unroll
        for (int kk = 0; kk < 2; kk++) {
            short8 a = *(const short8*)(Agg + (w * 16 + m) * 72 + kk * 32 + quad * 8);
            #pragma unroll
            for (int c = 0; c < 4; c++) {
                short8 b = Wf[((c * 2 + kk) * 4 + quad) * 16 + m];
                acc[c] = __builtin_amdgcn_mfma_f32_16x16x32_bf16(a, b, acc[c], 0, 0, 0);
            }
        }
        bool dzr[4];
        #pragma unroll
        for (int r = 0; r < 4; r++) {
            int row = row0 + quad * 4 + r;
            dzr[r] = (row < N) ? (off[row + 1] == off[row]) : false;
        }
        #pragma unroll
        for (int c = 0; c < 4; c++) {
            int col = c * 16 + m;
            float bv = b2[col];
            #pragma unroll
            for (int r = 0; r < 4; r++) {
                int rl = w * 16 + quad * 4 + r;
                float v = dzr[r] ? 0.5f : sigmoidf(acc[c][r] + bv);
                T2[rl * 72 + col] = f2bf(v);
            }
        }
    }

    // ---- phases 1&2 split-K: per half, H3h = relu(T2@W3half+b3half),
    //      then acc2 += H3h @ W4[khalf] ----
    floatx4 acc2[3];
    #pragma unroll
    for (int c = 0; c < 3; c++) acc2[c] = (floatx4){0.f, 0.f, 0.f, 0.f};
    const short8* Wf3 = (const short8*)(img + W3F_OFF);
    const short8* Wf4 = (const short8*)(img + W4F_OFF);

    #pragma unroll
    for (int half = 0; half < 2; half++) {
        floatx4 acc[4];
        #pragma unroll
        for (int c = 0; c < 4; c++) acc[c] = (floatx4){0.f, 0.f, 0.f, 0.f};
        #pragma unroll
        for (int kk = 0; kk < 2; kk++) {
            short8 a = *(const short8*)(T2 + (w * 16 + m) * 72 + kk * 32 + quad * 8);
            #pragma unroll
            for (int c = 0; c < 4; c++) {
                short8 b = Wf3[(((half * 4 + c) * 2 + kk) * 4 + quad) * 16 + m];
                acc[c] = __builtin_amdgcn_mfma_f32_16x16x32_bf16(a, b, acc[c], 0, 0, 0);
            }
        }
        #pragma unroll
        for (int c = 0; c < 4; c++) {
            int col = c * 16 + m;
            float bv = b3[half * 64 + col];
            #pragma unroll
            for (int r = 0; r < 4; r++) {
                int rl = w * 16 + quad * 4 + r;
                H3h[rl * 72 + col] = f2bf(fmaxf(acc[c][r] + bv, 0.f));
            }
        }
        #pragma unroll
        for (int kk2 = 0; kk2 < 2; kk2++) {
            short8 a = *(const short8*)(H3h + (w * 16 + m) * 72 + kk2 * 32 + quad * 8);
            #pragma unroll
            for (int c = 0; c < 3; c++) {
                short8 b = Wf4[((c * 4 + half * 2 + kk2) * 4 + quad) * 16 + m];
                acc2[c] = __builtin_amdgcn_mfma_f32_16x16x32_bf16(a, b, acc2[c], 0, 0, 0);
            }
        }
    }

    // ---- store out = acc2 + b4 ----
    #pragma unroll
    for (int c = 0; c < 3; c++) {
        int col = c * 16 + m;
        if (col < 40) {
            float bv = b4[col];
            #pragma unroll
            for (int r = 0; r < 4; r++) {
                int row = row0 + quad * 4 + r;
                if (row < N) out[(size_t)row * 40 + col] = acc2[c][r] + bv;
            }
        }
    }
}

extern "C" void kernel_launch(void* const* d_in, const int* in_sizes, int n_in,
                              void* d_out, int out_size, void* d_ws, size_t ws_size,
                              hipStream_t stream)
{
    const float* feat = (const float*)d_in[0];
    const int*   eidx = (const int*)d_in[1];
    const float* W1 = (const float*)d_in[2];
    const float* b1 = (const float*)d_in[3];
    const float* W2 = (const float*)d_in[4];
    const float* b2 = (const float*)d_in[5];
    const float* W3 = (const float*)d_in[6];
    const float* b3 = (const float*)d_in[7];
    const float* W4 = (const float*)d_in[8];
    const float* b4 = (const float*)d_in[9];

    const int N = in_sizes[0] / 64;
    const int E = in_sizes[1] / 2;
    const int* src = eidx;
    const int* dst = eidx + E;

    const int NBUCK = (N + CNODES - 1) / CNODES;   // 391

    unsigned short* featbf = (unsigned short*)d_ws;            // N*64 bf16
    unsigned short* t1     = featbf + (size_t)N * 64;          // N*64 bf16
    unsigned short* img    = t1     + (size_t)N * 64;          // WIMG_TOT
    int*   off   = (int*)(img + WIMG_TOT);                     // N+1
    int*   ccur  = off + (N + 1);                              // NBUCK
    int*   ssrc  = ccur + NBUCK;                               // E
    int*   arena = ssrc + E;                                   // NBUCK*CAP
    float* out   = (float*)d_out;

    const int gP  = (E + EPB - 1) / EPB;           // 391
    const int n8  = N * 64 / 8;
    const int g32 = (N + 31) / 32;
    const int G   = (gP > NBUCK) ? gP : NBUCK;     // 391

    // single cooperative prep: zero + partition + cast/img + per-bucket sort
    {
        int E_ = E, N_ = N, NBUCK_ = NBUCK, gP_ = gP, n8_ = n8;
        void* args[] = {
            (void*)&src, (void*)&dst, (void*)&ccur, (void*)&arena,
            (void*)&off, (void*)&ssrc, (void*)&E_, (void*)&N_, (void*)&NBUCK_,
            (void*)&gP_, (void*)&feat, (void*)&featbf,
            (void*)&W1, (void*)&W2, (void*)&W3, (void*)&W4,
            (void*)&img, (void*)&n8_
        };
        hipLaunchCooperativeKernel((const void*)prep_all_k, dim3(G), dim3(PTHR),
                                   args, 0, stream);
    }

    // t1 = sigmoid(mean(featbf[src]) @ W1 + b1)   [fused, 0 barriers]
    aggemm1_k<<<g32, dim3(128), 0, stream>>>(featbf, off, ssrc, img, b1, t1, N);
    // out = relu(sigmoid(mean(t1[src])@W2+b2)@W3+b3)@W4 + b4  [fused, 0 barriers]
    aggep3_k<<<g32, dim3(128), 0, stream>>>(t1, off, ssrc, img, b2, b3, b4, out, N);
}

// Round 13
// 206.905 us; speedup vs baseline: 2.0907x; 2.0907x over previous
//
#include <hip/hip_runtime.h>

// HGCN on MI355X. logmap0(expmap0(v)) == v here, so the model reduces to:
//   t1 = sigmoid(segmean(feat@W1+b1)); t2 = sigmoid(segmean(t1@W2+b2))
//   out = relu(t2@W3+b3)@W4 + b4     (segmean commutes with the linear map;
//   deg-0 nodes: segmean = 0 -> value 0.5 exactly, handled via dz check)
// R1-R13: see session journal. R14: re-anchor 229.4us.
// R15/R16: FAILED. R17: WIN (219). R18: partial. R19/R20: NULL.
// R21: 211.7 BEST (CSHIFT=8 split prep; gathers 128thr/32row @ 48us).
// R22: FAILED (367; 4B scatter write-amp). R23: FAILED (1315; LDS atomic
//   throughput ~3.6cyc/lane-op is a HW wall). R24: NULL -> GATHER DECLARED
//   ROOFLINED (~2TB/s random fabric, FETCH ~80MB; 5 attacks null).
// R25: FAILED (432; cooperative mega-kernel -> VGPR 20 = pk/bk arrays
//   spilled to scratch, 253us prep). Reverted per pre-commit.
// R26: fuse csr_fine INTO aggemm1. Blocks become bucket-aligned (256 rows,
//   512thr, grid 391, 42KB LDS -> 3 blocks/CU, co-resident): sort own
//   bucket (histogram/scan/scatter; off+ssrc still written for aggep3),
//   then gather via LDS-local beg/cnt (no cross-block off race), then
//   MFMA x2 sub-tiles. Sort latency hides under fabric-bound gather;
//   serial csr_fine stage eliminated. part_prep/aggep3 = R21 verbatim.
//   Pre-commit: aggemm1s>65 => fusion failed; total>=212 => revert+final.
//   Predicted 211.7 -> ~180-195.

constexpr int CSHIFT = 8;               // 256 nodes per coarse bucket
constexpr int CNODES = 1 << CSHIFT;
constexpr int EPB    = 4096;            // edges per partition block
constexpr int PTHR   = 512;             // partition block threads
constexpr int EPT    = EPB / PTHR;      // 8 edges/thread
constexpr int CAP    = 6144;            // arena cap/bucket (mean 4082)

// frag-packed bf16 weight image (shorts). Fragment = 16 lanes x 8 shorts =
// 128 shorts; flat idx = (((c*KK + kk)*4 + quad)*16 + m)*8 + j.
constexpr int W1F_OFF = 0;              // 4x2x4 frags  = 4096 shorts
constexpr int W2F_OFF = 4096;           // 4096
constexpr int W3F_OFF = 8192;           // 8x2x4 frags  = 8192
constexpr int W4F_OFF = 16384;          // 3x4x4 frags  = 6144 (cols padded 48)
constexpr int WIMG_TOT = 22528;

typedef __attribute__((ext_vector_type(8))) short short8;   // 8 bf16
typedef __attribute__((ext_vector_type(4))) float floatx4;  // MFMA acc

__device__ __forceinline__ float sigmoidf(float x) {
    return 1.0f / (1.0f + __expf(-x));
}
__device__ __forceinline__ unsigned short f2bf(float f) {   // RNE f32->bf16
    unsigned int u = __float_as_uint(f);
    u = (u + 0x7FFFu + ((u >> 16) & 1u)) >> 16;
    return (unsigned short)u;
}

// ---------------- CSR partition + one-time prep (merged launch, R21) -------
__global__ __launch_bounds__(512) void part_prep_k(
    const int* __restrict__ src, const int* __restrict__ dst,
    int* __restrict__ ccur, int* __restrict__ arena, int E, int NBUCK, int gP,
    const float* __restrict__ feat, unsigned short* __restrict__ featbf,
    const float* __restrict__ W1, const float* __restrict__ W2,
    const float* __restrict__ W3, const float* __restrict__ W4,
    unsigned short* __restrict__ img, int n8)
{
    __shared__ int  hist[512];
    __shared__ int  exoff[512];
    __shared__ int  lcur[512];
    __shared__ int  gbase[512];
    __shared__ int  wsum[8];
    __shared__ int  stage[EPB];
    __shared__ unsigned short stageS[EPB];   // bucket id (up to 390)

    const int tid = threadIdx.x;

    if ((int)blockIdx.x >= gP) {
        // ---- prep path ----
        int i = ((int)blockIdx.x - gP) * PTHR + tid;
        if (i < n8) {
            const float4* p = (const float4*)feat + (size_t)i * 2;
            float4 a = p[0], b = p[1];
            uint4 o;
            o.x = (unsigned)f2bf(a.x) | ((unsigned)f2bf(a.y) << 16);
            o.y = (unsigned)f2bf(a.z) | ((unsigned)f2bf(a.w) << 16);
            o.z = (unsigned)f2bf(b.x) | ((unsigned)f2bf(b.y) << 16);
            o.w = (unsigned)f2bf(b.z) | ((unsigned)f2bf(b.w) << 16);
            ((uint4*)featbf)[i] = o;
            return;
        }
        int t = i - n8;
        if (t >= WIMG_TOT) return;
        float v = 0.f;
        int s = t;
        if (s < W2F_OFF) {                       // W1 [64x64]
            int j = s & 7, m = (s >> 3) & 15, q = (s >> 7) & 3, kk = (s >> 9) & 1, c = s >> 10;
            v = W1[(kk * 32 + q * 8 + j) * 64 + c * 16 + m];
        } else if (s < W3F_OFF) {                // W2 [64x64]
            s -= W2F_OFF;
            int j = s & 7, m = (s >> 3) & 15, q = (s >> 7) & 3, kk = (s >> 9) & 1, c = s >> 10;
            v = W2[(kk * 32 + q * 8 + j) * 64 + c * 16 + m];
        } else if (s < W4F_OFF) {                // W3 [64x128]
            s -= W3F_OFF;
            int j = s & 7, m = (s >> 3) & 15, q = (s >> 7) & 3, kk = (s >> 9) & 1, c = s >> 10;
            v = W3[(kk * 32 + q * 8 + j) * 128 + c * 16 + m];
        } else {                                 // W4 [128x40], cols padded 48
            s -= W4F_OFF;
            int j = s & 7, m = (s >> 3) & 15, q = (s >> 7) & 3, kk = (s >> 9) & 3, c = s >> 11;
            int n = c * 16 + m;
            if (n < 40) v = W4[(kk * 32 + q * 8 + j) * 40 + n];
        }
        img[t] = f2bf(v);
        return;
    }

    // ---- partition path (512 threads, 512-entry hist) ----
    const int e0  = blockIdx.x * EPB;
    const int ec  = min(EPB, E - e0);
    const int lane = tid & 63, wid = tid >> 6;

    int pk[EPT], bk[EPT];
    hist[tid] = 0;
    __syncthreads();
    #pragma unroll
    for (int j = 0; j < EPT; j++) {
        int idx = tid + j * PTHR;
        if (idx < ec) {
            int s = src[e0 + idx];
            int d = dst[e0 + idx];
            bk[j] = d >> CSHIFT;
            pk[j] = s | ((d & (CNODES - 1)) << 17);
            atomicAdd(&hist[bk[j]], 1);
        } else bk[j] = -1;
    }
    __syncthreads();
    int h = hist[tid];
    int v = h;
    #pragma unroll
    for (int d = 1; d < 64; d <<= 1) {
        int t = __shfl_up(v, d);
        if (lane >= d) v += t;
    }
    if (lane == 63) wsum[wid] = v;
    __syncthreads();
    if (tid == 0) {
        int s = 0;
        #pragma unroll
        for (int k = 0; k < 8; k++) { int t = wsum[k]; wsum[k] = s; s += t; }
    }
    __syncthreads();
    {
        int ex = wsum[wid] + v - h;
        int gb = 0;
        if (tid < NBUCK && h > 0) gb = atomicAdd(ccur + tid, h);
        exoff[tid] = ex;
        lcur[tid]  = ex;
        gbase[tid] = gb;
    }
    __syncthreads();
    #pragma unroll
    for (int j = 0; j < EPT; j++) {
        if (bk[j] >= 0) {
            int l = atomicAdd(&lcur[bk[j]], 1);
            stage[l]  = pk[j];
            stageS[l] = (unsigned short)bk[j];
        }
    }
    __syncthreads();
    for (int i = tid; i < ec; i += PTHR) {
        int b = stageS[i];
        arena[(size_t)b * CAP + gbase[b] + (i - exoff[b])] = stage[i];
    }
}

// ---------------- proven 8-deep gather of one row range --------------------
// ROOFLINED inner loop (R17/R21/R24) -- do not modify.
#define ACC8(v)                                    \
    acc[0] += __uint_as_float((v).x << 16);        \
    acc[1] += __uint_as_float((v).x & 0xFFFF0000u);\
    acc[2] += __uint_as_float((v).y << 16);        \
    acc[3] += __uint_as_float((v).y & 0xFFFF0000u);\
    acc[4] += __uint_as_float((v).z << 16);        \
    acc[5] += __uint_as_float((v).z & 0xFFFF0000u);\
    acc[6] += __uint_as_float((v).w << 16);        \
    acc[7] += __uint_as_float((v).w & 0xFFFF0000u);

__device__ __forceinline__ uint4 gather_row(
    const unsigned short* __restrict__ h, const int* __restrict__ ssrc,
    int beg, int end, int q)
{
    float acc[8] = {0.f, 0.f, 0.f, 0.f, 0.f, 0.f, 0.f, 0.f};
    int i = beg;
    for (; i + 8 <= end; i += 8) {       // 8 loads in flight per lane
        uint4 v0 = *(const uint4*)(h + (size_t)ssrc[i]     * 64 + q);
        uint4 v1 = *(const uint4*)(h + (size_t)ssrc[i + 1] * 64 + q);
        uint4 v2 = *(const uint4*)(h + (size_t)ssrc[i + 2] * 64 + q);
        uint4 v3 = *(const uint4*)(h + (size_t)ssrc[i + 3] * 64 + q);
        uint4 v4 = *(const uint4*)(h + (size_t)ssrc[i + 4] * 64 + q);
        uint4 v5 = *(const uint4*)(h + (size_t)ssrc[i + 5] * 64 + q);
        uint4 v6 = *(const uint4*)(h + (size_t)ssrc[i + 6] * 64 + q);
        uint4 v7 = *(const uint4*)(h + (size_t)ssrc[i + 7] * 64 + q);
        ACC8(v0); ACC8(v1); ACC8(v2); ACC8(v3);
        ACC8(v4); ACC8(v5); ACC8(v6); ACC8(v7);
    }
    for (; i + 2 <= end; i += 2) {
        uint4 v0 = *(const uint4*)(h + (size_t)ssrc[i]     * 64 + q);
        uint4 v1 = *(const uint4*)(h + (size_t)ssrc[i + 1] * 64 + q);
        ACC8(v0); ACC8(v1);
    }
    for (; i < end; i++) {
        uint4 v = *(const uint4*)(h + (size_t)ssrc[i] * 64 + q);
        ACC8(v);
    }
    // v_rcp_f32: 2^-22 rel err, absorbed by the bf16 round
    float inv = __builtin_amdgcn_rcpf((float)max(end - beg, 1));
    uint4 p;
    p.x = (unsigned)f2bf(acc[0]*inv) | ((unsigned)f2bf(acc[1]*inv) << 16);
    p.y = (unsigned)f2bf(acc[2]*inv) | ((unsigned)f2bf(acc[3]*inv) << 16);
    p.z = (unsigned)f2bf(acc[4]*inv) | ((unsigned)f2bf(acc[5]*inv) << 16);
    p.w = (unsigned)f2bf(acc[6]*inv) | ((unsigned)f2bf(acc[7]*inv) << 16);
    return p;
}

// ---------------- fused bucket-sort + gather + GEMM1 + sigmoid -> t1 -------
// R26: one block per 256-node bucket (512 thr, grid 391). Sort own bucket
// (writing off/ssrc for aggep3), then gather via LDS-local beg/cnt, then
// MFMA for 2 sub-tiles per wave. ~42KB LDS -> 3 blocks/CU, co-resident.
__global__ __launch_bounds__(512) void aggemm1s_k(
    const unsigned short* __restrict__ featbf, const int* __restrict__ ccur,
    const int* __restrict__ arena, int* __restrict__ off,
    int* __restrict__ ssrc, const unsigned short* __restrict__ img,
    const float* __restrict__ bias, unsigned short* __restrict__ t1,
    int N, int E, int NBUCK)
{
    __shared__ int part[512];
    __shared__ int wsum[8];
    __shared__ int cnt[CNODES];
    __shared__ int beg2[CNODES];
    __shared__ int cur[CNODES];
    __shared__ int wpre2[4];
    __shared__ alignas(16) unsigned short Agg[CNODES * 72];   // 36.9 KB

    const int tid = threadIdx.x;
    const int bid = blockIdx.x;
    const int lane = tid & 63, wid = tid >> 6;
    const int rowB = bid << CSHIFT;

    // ---- cross-bucket exclusive prefix of ccur -> cbeg ----
    int c0 = (tid < NBUCK) ? ccur[tid] : 0;
    int v0 = c0;
    #pragma unroll
    for (int d = 1; d < 64; d <<= 1) {
        int t = __shfl_up(v0, d);
        if (lane >= d) v0 += t;
    }
    if (lane == 63) wsum[wid] = v0;
    __syncthreads();
    if (tid == 0) {
        int s = 0;
        #pragma unroll
        for (int k = 0; k < 8; k++) { int t = wsum[k]; wsum[k] = s; s += t; }
    }
    __syncthreads();
    part[tid] = wsum[wid] + v0;                  // inclusive prefix
    __syncthreads();
    const int cbeg = (bid > 0) ? part[bid - 1] : 0;
    const int ec   = min(ccur[bid], CAP);
    if (bid == 0 && tid == 0) off[N] = E;

    // ---- histogram over this bucket's arena region ----
    if (tid < CNODES) cnt[tid] = 0;
    __syncthreads();
    const int* pe = arena + (size_t)bid * CAP;
    for (int i = tid; i < ec; i += 512)
        atomicAdd(&cnt[(pe[i] >> 17) & (CNODES - 1)], 1);
    __syncthreads();

    // ---- scan cnt[256] on waves 0-3 -> beg2/cur; publish off ----
    int c = 0, v = 0;
    if (tid < CNODES) {
        c = cnt[tid];
        v = c;
        #pragma unroll
        for (int d = 1; d < 64; d <<= 1) {
            int t = __shfl_up(v, d);
            if (lane >= d) v += t;
        }
        if (lane == 63) wpre2[wid] = v;
    }
    __syncthreads();
    if (tid == 0) {
        int s = 0;
        #pragma unroll
        for (int k = 0; k < CNODES / 64; k++) { int t = wpre2[k]; wpre2[k] = s; s += t; }
    }
    __syncthreads();
    if (tid < CNODES) {
        int ex = wpre2[wid] + v - c;
        beg2[tid] = ex;
        cur[tid]  = ex;
        int node = rowB + tid;
        if (node < N) off[node] = cbeg + ex;     // for aggep3
    }
    __syncthreads();

    // ---- scatter sorted src ids to global ssrc ----
    for (int i = tid; i < ec; i += 512) {
        int p = pe[i];
        int pos = cbeg + atomicAdd(&cur[(p >> 17) & (CNODES - 1)], 1);
        ssrc[pos] = p & 0x1FFFF;
    }
    __syncthreads();

    // ---- gather: wave w owns rows w*32..w*32+31 (4 passes x 8 rows) ----
    const int w = wid;
    const int q = (lane & 7) * 8;
    #pragma unroll
    for (int pass = 0; pass < 4; pass++) {
        int rl = w * 32 + pass * 8 + (lane >> 3);
        int g  = rowB + rl;
        uint4 p = make_uint4(0u, 0u, 0u, 0u);
        if (g < N) {
            int beg = cbeg + beg2[rl];
            int end = beg + cnt[rl];
            p = gather_row(featbf, ssrc, beg, end, q);
        }
        *(uint4*)(Agg + rl * 72 + q) = p;
    }
    // Agg rows wave-local -> no barrier needed (in-wave lgkmcnt ordering)

    // ---- GEMM1 + sigmoid for 2 sub-tiles (16 rows each) per wave ----
    const int m = lane & 15, quad = lane >> 4;
    const short8* Wf = (const short8*)(img + W1F_OFF);
    #pragma unroll
    for (int sub = 0; sub < 2; sub++) {
        const int r0l = w * 32 + sub * 16;
        floatx4 acc[4];
        #pragma unroll
        for (int cc = 0; cc < 4; cc++) acc[cc] = (floatx4){0.f, 0.f, 0.f, 0.f};
        #pragma unroll
        for (int kk = 0; kk < 2; kk++) {
            short8 a = *(const short8*)(Agg + (r0l + m) * 72 + kk * 32 + quad * 8);
            #pragma unroll
            for (int cc = 0; cc < 4; cc++) {
                short8 b = Wf[((cc * 2 + kk) * 4 + quad) * 16 + m];
                acc[cc] = __builtin_amdgcn_mfma_f32_16x16x32_bf16(a, b, acc[cc], 0, 0, 0);
            }
        }
        bool dzr[4];
        int rows[4];
        #pragma unroll
        for (int r = 0; r < 4; r++) {
            int rl = r0l + quad * 4 + r;
            rows[r] = rowB + rl;
            dzr[r] = (cnt[rl] == 0);
        }
        #pragma unroll
        for (int cc = 0; cc < 4; cc++) {
            int col = cc * 16 + m;
            float bv = bias[col];
            #pragma unroll
            for (int r = 0; r < 4; r++) {
                if (rows[r] < N) {
                    float vv = dzr[r] ? 0.5f : sigmoidf(acc[cc][r] + bv);
                    t1[(size_t)rows[r] * 64 + col] = f2bf(vv);
                }
            }
        }
    }
}

// ---------------- wave-local gather wrapper for aggep3 (R21 form) ----------
__device__ __forceinline__ void gather_tile_wave(
    const unsigned short* __restrict__ h, const int* __restrict__ off,
    const int* __restrict__ ssrc, unsigned short* Agg, int rowB, int N,
    int w, int lane)
{
    #pragma unroll
    for (int pass = 0; pass < 2; pass++) {
        int rl = w * 16 + pass * 8 + (lane >> 3);
        int g  = rowB + rl;
        int q  = (lane & 7) * 8;
        uint4 p = make_uint4(0u, 0u, 0u, 0u);
        if (g < N) {
            p = gather_row(h, ssrc, off[g], off[g + 1], q);
        }
        *(uint4*)(Agg + rl * 72 + q) = p;
    }
}

// ---------------- fused gather + triple-GEMM -> out (R21 verbatim) ---------
// 128 threads / 32-row tile; LDS: T2[0,2304) | Agg/H3h[2304,4608) shorts.
__global__ __launch_bounds__(128) void aggep3_k(
    const unsigned short* __restrict__ t1, const int* __restrict__ off,
    const int* __restrict__ ssrc, const unsigned short* __restrict__ img,
    const float* __restrict__ b2, const float* __restrict__ b3,
    const float* __restrict__ b4, float* __restrict__ out, int N)
{
    __shared__ alignas(16) unsigned short SM[4608];   // 9.2 KB
    unsigned short* T2  = SM;            // 32 x 72
    unsigned short* Agg = SM + 2304;     // 32 x 72 (dead after phase 0)
    unsigned short* H3h = SM + 2304;     // aliases Agg

    const int tid = threadIdx.x;
    const int rowB = blockIdx.x * 32;
    const int w = tid >> 6, lane = tid & 63;
    const int m = lane & 15, quad = lane >> 4;
    const int row0 = rowB + w * 16;

    gather_tile_wave(t1, off, ssrc, Agg, rowB, N, w, lane);

    // ---- phase 0: T2 = sigmoid(Agg @ W2 + b2) ----
    {
        const short8* Wf = (const short8*)(img + W2F_OFF);
        floatx4 acc[4];
        #pragma unroll
        for (int c = 0; c < 4; c++) acc[c] = (floatx4){0.f, 0.f, 0.f, 0.f};
        #pragma unroll
        for (int kk = 0; kk < 2; kk++) {
            short8 a = *(const short8*)(Agg + (w * 16 + m) * 72 + kk * 32 + quad * 8);
            #pragma unroll
            for (int c = 0; c < 4; c++) {
                short8 b = Wf[((c * 2 + kk) * 4 + quad) * 16 + m];
                acc[c] = __builtin_amdgcn_mfma_f32_16x16x32_bf16(a, b, acc[c], 0, 0, 0);
            }
        }
        bool dzr[4];
        #pragma unroll
        for (int r = 0; r < 4; r++) {
            int row = row0 + quad * 4 + r;
            dzr[r] = (row < N) ? (off[row + 1] == off[row]) : false;
        }
        #pragma unroll
        for (int c = 0; c < 4; c++) {
            int col = c * 16 + m;
            float bv = b2[col];
            #pragma unroll
            for (int r = 0; r < 4; r++) {
                int rl = w * 16 + quad * 4 + r;
                float v = dzr[r] ? 0.5f : sigmoidf(acc[c][r] + bv);
                T2[rl * 72 + col] = f2bf(v);
            }
        }
    }

    // ---- phases 1&2 split-K: per half, H3h = relu(T2@W3half+b3half),
    //      then acc2 += H3h @ W4[khalf] ----
    floatx4 acc2[3];
    #pragma unroll
    for (int c = 0; c < 3; c++) acc2[c] = (floatx4){0.f, 0.f, 0.f, 0.f};
    const short8* Wf3 = (const short8*)(img + W3F_OFF);
    const short8* Wf4 = (const short8*)(img + W4F_OFF);

    #pragma unroll
    for (int half = 0; half < 2; half++) {
        floatx4 acc[4];
        #pragma unroll
        for (int c = 0; c < 4; c++) acc[c] = (floatx4){0.f, 0.f, 0.f, 0.f};
        #pragma unroll
        for (int kk = 0; kk < 2; kk++) {
            short8 a = *(const short8*)(T2 + (w * 16 + m) * 72 + kk * 32 + quad * 8);
            #pragma unroll
            for (int c = 0; c < 4; c++) {
                short8 b = Wf3[(((half * 4 + c) * 2 + kk) * 4 + quad) * 16 + m];
                acc[c] = __builtin_amdgcn_mfma_f32_16x16x32_bf16(a, b, acc[c], 0, 0, 0);
            }
        }
        #pragma unroll
        for (int c = 0; c < 4; c++) {
            int col = c * 16 + m;
            float bv = b3[half * 64 + col];
            #pragma unroll
            for (int r = 0; r < 4; r++) {
                int rl = w * 16 + quad * 4 + r;
                H3h[rl * 72 + col] = f2bf(fmaxf(acc[c][r] + bv, 0.f));
            }
        }
        #pragma unroll
        for (int kk2 = 0; kk2 < 2; kk2++) {
            short8 a = *(const short8*)(H3h + (w * 16 + m) * 72 + kk2 * 32 + quad * 8);
            #pragma unroll
            for (int c = 0; c < 3; c++) {
                short8 b = Wf4[((c * 4 + half * 2 + kk2) * 4 + quad) * 16 + m];
                acc2[c] = __builtin_amdgcn_mfma_f32_16x16x32_bf16(a, b, acc2[c], 0, 0, 0);
            }
        }
    }

    // ---- store out = acc2 + b4 ----
    #pragma unroll
    for (int c = 0; c < 3; c++) {
        int col = c * 16 + m;
        if (col < 40) {
            float bv = b4[col];
            #pragma unroll
            for (int r = 0; r < 4; r++) {
                int row = row0 + quad * 4 + r;
                if (row < N) out[(size_t)row * 40 + col] = acc2[c][r] + bv;
            }
        }
    }
}

extern "C" void kernel_launch(void* const* d_in, const int* in_sizes, int n_in,
                              void* d_out, int out_size, void* d_ws, size_t ws_size,
                              hipStream_t stream)
{
    const float* feat = (const float*)d_in[0];
    const int*   eidx = (const int*)d_in[1];
    const float* W1 = (const float*)d_in[2];
    const float* b1 = (const float*)d_in[3];
    const float* W2 = (const float*)d_in[4];
    const float* b2 = (const float*)d_in[5];
    const float* W3 = (const float*)d_in[6];
    const float* b3 = (const float*)d_in[7];
    const float* W4 = (const float*)d_in[8];
    const float* b4 = (const float*)d_in[9];

    const int N = in_sizes[0] / 64;
    const int E = in_sizes[1] / 2;
    const int* src = eidx;
    const int* dst = eidx + E;

    const int NBUCK = (N + CNODES - 1) / CNODES;   // 391

    unsigned short* featbf = (unsigned short*)d_ws;            // N*64 bf16
    unsigned short* t1     = featbf + (size_t)N * 64;          // N*64 bf16
    unsigned short* img    = t1     + (size_t)N * 64;          // WIMG_TOT
    int*   off   = (int*)(img + WIMG_TOT);                     // N+1
    int*   ccur  = off + (N + 1);                              // NBUCK
    int*   ssrc  = ccur + NBUCK;                               // E
    int*   arena = ssrc + E;                                   // NBUCK*CAP
    float* out   = (float*)d_out;

    hipMemsetAsync(ccur, 0, (size_t)NBUCK * sizeof(int), stream);

    const int gP  = (E + EPB - 1) / EPB;           // 391
    const int n8  = N * 64 / 8;
    const int g32 = (N + 31) / 32;
    const int gPC = (n8 + WIMG_TOT + PTHR - 1) / PTHR;

    // CSR partition + prep (merged, 512thr)  [R21 verbatim]
    part_prep_k<<<gP + gPC, dim3(PTHR), 0, stream>>>(src, dst, ccur, arena, E,
                                                     NBUCK, gP, feat, featbf,
                                                     W1, W2, W3, W4, img, n8);

    // fused: per-bucket sort (writes off/ssrc) + gather + GEMM1 -> t1  [R26]
    aggemm1s_k<<<NBUCK, dim3(512), 0, stream>>>(featbf, ccur, arena, off, ssrc,
                                                img, b1, t1, N, E, NBUCK);

    // out = relu(sigmoid(mean(t1[src])@W2+b2)@W3+b3)@W4 + b4  [R21 verbatim]
    aggep3_k<<<g32, dim3(128), 0, stream>>>(t1, off, ssrc, img, b2, b3, b4, out, N);
}

// Round 14
// 204.397 us; speedup vs baseline: 2.1163x; 1.0123x over previous
//
#include <hip/hip_runtime.h>

// HGCN on MI355X. logmap0(expmap0(v)) == v here, so the model reduces to:
//   t1 = sigmoid(segmean(feat@W1+b1)); t2 = sigmoid(segmean(t1@W2+b2))
//   out = relu(t2@W3+b3)@W4 + b4     (segmean commutes with the linear map;
//   deg-0 nodes: segmean = 0 -> value 0.5 exactly, handled via dz check)
// R1-R13: see session journal. R14: re-anchor 229.4us.
// R15/R16: FAILED. R17: WIN (219). R18: partial. R19/R20: NULL.
// R21: 211.7 (CSHIFT=8 split prep). R22: FAILED (4B scatter write-amp).
// R23: FAILED (LDS atomic throughput ~3.6cyc/lane-op = HW wall).
// R24: NULL -> GATHER ROOFLINED (~2TB/s random fabric, FETCH ~80MB).
// R25: FAILED (coop mega-kernel spilled, VGPR 20).
// R26: WIN (206.9). csr_fine fused into aggemm1 (bucket-aligned 512thr
//   blocks sort own bucket then gather+MFMA); sort hid under fabric-bound
//   gather (+6us vs +45 serial). Dispatches 5->4.
// R27: part_prep radix with 1 LDS atomic/edge (was 2): pass A takes
//   rank=atomicAdd(&hist[b],1) and KEEPS rank in registers (rk[8]); stage
//   slot = exoff[b]+rank after the scan -- lcur atomic deleted. Halves
//   radix LDS-atomic load (R23 constant: 3.6cyc/lane-op => ~9us saved).
//   aggemm1s/aggep3 untouched (rooflined). Pre-commit: part_prep
//   unchanged => latency-bound, declare structural floor next round.
//   Predicted 206.9 -> ~197-202.

constexpr int CSHIFT = 8;               // 256 nodes per coarse bucket
constexpr int CNODES = 1 << CSHIFT;
constexpr int EPB    = 4096;            // edges per partition block
constexpr int PTHR   = 512;             // partition block threads
constexpr int EPT    = EPB / PTHR;      // 8 edges/thread
constexpr int CAP    = 6144;            // arena cap/bucket (mean 4082)

// frag-packed bf16 weight image (shorts). Fragment = 16 lanes x 8 shorts =
// 128 shorts; flat idx = (((c*KK + kk)*4 + quad)*16 + m)*8 + j.
constexpr int W1F_OFF = 0;              // 4x2x4 frags  = 4096 shorts
constexpr int W2F_OFF = 4096;           // 4096
constexpr int W3F_OFF = 8192;           // 8x2x4 frags  = 8192
constexpr int W4F_OFF = 16384;          // 3x4x4 frags  = 6144 (cols padded 48)
constexpr int WIMG_TOT = 22528;

typedef __attribute__((ext_vector_type(8))) short short8;   // 8 bf16
typedef __attribute__((ext_vector_type(4))) float floatx4;  // MFMA acc

__device__ __forceinline__ float sigmoidf(float x) {
    return 1.0f / (1.0f + __expf(-x));
}
__device__ __forceinline__ unsigned short f2bf(float f) {   // RNE f32->bf16
    unsigned int u = __float_as_uint(f);
    u = (u + 0x7FFFu + ((u >> 16) & 1u)) >> 16;
    return (unsigned short)u;
}

// ---------------- CSR partition + one-time prep (merged launch) ------------
// R27: single-atomic radix -- rank captured in pass A, no lcur pass.
__global__ __launch_bounds__(512) void part_prep_k(
    const int* __restrict__ src, const int* __restrict__ dst,
    int* __restrict__ ccur, int* __restrict__ arena, int E, int NBUCK, int gP,
    const float* __restrict__ feat, unsigned short* __restrict__ featbf,
    const float* __restrict__ W1, const float* __restrict__ W2,
    const float* __restrict__ W3, const float* __restrict__ W4,
    unsigned short* __restrict__ img, int n8)
{
    __shared__ int  hist[512];
    __shared__ int  exoff[512];
    __shared__ int  gbase[512];
    __shared__ int  wsum[8];
    __shared__ int  stage[EPB];
    __shared__ unsigned short stageS[EPB];   // bucket id (up to 390)

    const int tid = threadIdx.x;

    if ((int)blockIdx.x >= gP) {
        // ---- prep path ----
        int i = ((int)blockIdx.x - gP) * PTHR + tid;
        if (i < n8) {
            const float4* p = (const float4*)feat + (size_t)i * 2;
            float4 a = p[0], b = p[1];
            uint4 o;
            o.x = (unsigned)f2bf(a.x) | ((unsigned)f2bf(a.y) << 16);
            o.y = (unsigned)f2bf(a.z) | ((unsigned)f2bf(a.w) << 16);
            o.z = (unsigned)f2bf(b.x) | ((unsigned)f2bf(b.y) << 16);
            o.w = (unsigned)f2bf(b.z) | ((unsigned)f2bf(b.w) << 16);
            ((uint4*)featbf)[i] = o;
            return;
        }
        int t = i - n8;
        if (t >= WIMG_TOT) return;
        float v = 0.f;
        int s = t;
        if (s < W2F_OFF) {                       // W1 [64x64]
            int j = s & 7, m = (s >> 3) & 15, q = (s >> 7) & 3, kk = (s >> 9) & 1, c = s >> 10;
            v = W1[(kk * 32 + q * 8 + j) * 64 + c * 16 + m];
        } else if (s < W3F_OFF) {                // W2 [64x64]
            s -= W2F_OFF;
            int j = s & 7, m = (s >> 3) & 15, q = (s >> 7) & 3, kk = (s >> 9) & 1, c = s >> 10;
            v = W2[(kk * 32 + q * 8 + j) * 64 + c * 16 + m];
        } else if (s < W4F_OFF) {                // W3 [64x128]
            s -= W3F_OFF;
            int j = s & 7, m = (s >> 3) & 15, q = (s >> 7) & 3, kk = (s >> 9) & 1, c = s >> 10;
            v = W3[(kk * 32 + q * 8 + j) * 128 + c * 16 + m];
        } else {                                 // W4 [128x40], cols padded 48
            s -= W4F_OFF;
            int j = s & 7, m = (s >> 3) & 15, q = (s >> 7) & 3, kk = (s >> 9) & 3, c = s >> 11;
            int n = c * 16 + m;
            if (n < 40) v = W4[(kk * 32 + q * 8 + j) * 40 + n];
        }
        img[t] = f2bf(v);
        return;
    }

    // ---- partition path (512 threads, 512-entry hist, 1 atomic/edge) ----
    const int e0  = blockIdx.x * EPB;
    const int ec  = min(EPB, E - e0);
    const int lane = tid & 63, wid = tid >> 6;

    int pk[EPT], bk[EPT], rk[EPT];
    hist[tid] = 0;
    __syncthreads();
    #pragma unroll
    for (int j = 0; j < EPT; j++) {
        int idx = tid + j * PTHR;
        if (idx < ec) {
            int s = src[e0 + idx];
            int d = dst[e0 + idx];
            bk[j] = d >> CSHIFT;
            pk[j] = s | ((d & (CNODES - 1)) << 17);
            rk[j] = atomicAdd(&hist[bk[j]], 1);   // rank within bucket
        } else bk[j] = -1;
    }
    __syncthreads();
    int h = hist[tid];
    int v = h;
    #pragma unroll
    for (int d = 1; d < 64; d <<= 1) {
        int t = __shfl_up(v, d);
        if (lane >= d) v += t;
    }
    if (lane == 63) wsum[wid] = v;
    __syncthreads();
    if (tid == 0) {
        int s = 0;
        #pragma unroll
        for (int k = 0; k < 8; k++) { int t = wsum[k]; wsum[k] = s; s += t; }
    }
    __syncthreads();
    {
        int ex = wsum[wid] + v - h;
        int gb = 0;
        if (tid < NBUCK && h > 0) gb = atomicAdd(ccur + tid, h);
        exoff[tid] = ex;
        gbase[tid] = gb;
    }
    __syncthreads();
    #pragma unroll
    for (int j = 0; j < EPT; j++) {
        if (bk[j] >= 0) {
            int l = exoff[bk[j]] + rk[j];         // no atomic (R27)
            stage[l]  = pk[j];
            stageS[l] = (unsigned short)bk[j];
        }
    }
    __syncthreads();
    for (int i = tid; i < ec; i += PTHR) {
        int b = stageS[i];
        arena[(size_t)b * CAP + gbase[b] + (i - exoff[b])] = stage[i];
    }
}

// ---------------- proven 8-deep gather of one row range --------------------
// ROOFLINED inner loop (R17/R21/R24) -- do not modify.
#define ACC8(v)                                    \
    acc[0] += __uint_as_float((v).x << 16);        \
    acc[1] += __uint_as_float((v).x & 0xFFFF0000u);\
    acc[2] += __uint_as_float((v).y << 16);        \
    acc[3] += __uint_as_float((v).y & 0xFFFF0000u);\
    acc[4] += __uint_as_float((v).z << 16);        \
    acc[5] += __uint_as_float((v).z & 0xFFFF0000u);\
    acc[6] += __uint_as_float((v).w << 16);        \
    acc[7] += __uint_as_float((v).w & 0xFFFF0000u);

__device__ __forceinline__ uint4 gather_row(
    const unsigned short* __restrict__ h, const int* __restrict__ ssrc,
    int beg, int end, int q)
{
    float acc[8] = {0.f, 0.f, 0.f, 0.f, 0.f, 0.f, 0.f, 0.f};
    int i = beg;
    for (; i + 8 <= end; i += 8) {       // 8 loads in flight per lane
        uint4 v0 = *(const uint4*)(h + (size_t)ssrc[i]     * 64 + q);
        uint4 v1 = *(const uint4*)(h + (size_t)ssrc[i + 1] * 64 + q);
        uint4 v2 = *(const uint4*)(h + (size_t)ssrc[i + 2] * 64 + q);
        uint4 v3 = *(const uint4*)(h + (size_t)ssrc[i + 3] * 64 + q);
        uint4 v4 = *(const uint4*)(h + (size_t)ssrc[i + 4] * 64 + q);
        uint4 v5 = *(const uint4*)(h + (size_t)ssrc[i + 5] * 64 + q);
        uint4 v6 = *(const uint4*)(h + (size_t)ssrc[i + 6] * 64 + q);
        uint4 v7 = *(const uint4*)(h + (size_t)ssrc[i + 7] * 64 + q);
        ACC8(v0); ACC8(v1); ACC8(v2); ACC8(v3);
        ACC8(v4); ACC8(v5); ACC8(v6); ACC8(v7);
    }
    for (; i + 2 <= end; i += 2) {
        uint4 v0 = *(const uint4*)(h + (size_t)ssrc[i]     * 64 + q);
        uint4 v1 = *(const uint4*)(h + (size_t)ssrc[i + 1] * 64 + q);
        ACC8(v0); ACC8(v1);
    }
    for (; i < end; i++) {
        uint4 v = *(const uint4*)(h + (size_t)ssrc[i] * 64 + q);
        ACC8(v);
    }
    // v_rcp_f32: 2^-22 rel err, absorbed by the bf16 round
    float inv = __builtin_amdgcn_rcpf((float)max(end - beg, 1));
    uint4 p;
    p.x = (unsigned)f2bf(acc[0]*inv) | ((unsigned)f2bf(acc[1]*inv) << 16);
    p.y = (unsigned)f2bf(acc[2]*inv) | ((unsigned)f2bf(acc[3]*inv) << 16);
    p.z = (unsigned)f2bf(acc[4]*inv) | ((unsigned)f2bf(acc[5]*inv) << 16);
    p.w = (unsigned)f2bf(acc[6]*inv) | ((unsigned)f2bf(acc[7]*inv) << 16);
    return p;
}

// ---------------- fused bucket-sort + gather + GEMM1 + sigmoid -> t1 -------
// R26 (proven): one block per 256-node bucket (512 thr, grid 391). Sort own
// bucket (writing off/ssrc for aggep3), gather via LDS-local beg/cnt, MFMA.
__global__ __launch_bounds__(512) void aggemm1s_k(
    const unsigned short* __restrict__ featbf, const int* __restrict__ ccur,
    const int* __restrict__ arena, int* __restrict__ off,
    int* __restrict__ ssrc, const unsigned short* __restrict__ img,
    const float* __restrict__ bias, unsigned short* __restrict__ t1,
    int N, int E, int NBUCK)
{
    __shared__ int part[512];
    __shared__ int wsum[8];
    __shared__ int cnt[CNODES];
    __shared__ int beg2[CNODES];
    __shared__ int cur[CNODES];
    __shared__ int wpre2[4];
    __shared__ alignas(16) unsigned short Agg[CNODES * 72];   // 36.9 KB

    const int tid = threadIdx.x;
    const int bid = blockIdx.x;
    const int lane = tid & 63, wid = tid >> 6;
    const int rowB = bid << CSHIFT;

    // ---- cross-bucket exclusive prefix of ccur -> cbeg ----
    int c0 = (tid < NBUCK) ? ccur[tid] : 0;
    int v0 = c0;
    #pragma unroll
    for (int d = 1; d < 64; d <<= 1) {
        int t = __shfl_up(v0, d);
        if (lane >= d) v0 += t;
    }
    if (lane == 63) wsum[wid] = v0;
    __syncthreads();
    if (tid == 0) {
        int s = 0;
        #pragma unroll
        for (int k = 0; k < 8; k++) { int t = wsum[k]; wsum[k] = s; s += t; }
    }
    __syncthreads();
    part[tid] = wsum[wid] + v0;                  // inclusive prefix
    __syncthreads();
    const int cbeg = (bid > 0) ? part[bid - 1] : 0;
    const int ec   = min(ccur[bid], CAP);
    if (bid == 0 && tid == 0) off[N] = E;

    // ---- histogram over this bucket's arena region ----
    if (tid < CNODES) cnt[tid] = 0;
    __syncthreads();
    const int* pe = arena + (size_t)bid * CAP;
    for (int i = tid; i < ec; i += 512)
        atomicAdd(&cnt[(pe[i] >> 17) & (CNODES - 1)], 1);
    __syncthreads();

    // ---- scan cnt[256] on waves 0-3 -> beg2/cur; publish off ----
    int c = 0, v = 0;
    if (tid < CNODES) {
        c = cnt[tid];
        v = c;
        #pragma unroll
        for (int d = 1; d < 64; d <<= 1) {
            int t = __shfl_up(v, d);
            if (lane >= d) v += t;
        }
        if (lane == 63) wpre2[wid] = v;
    }
    __syncthreads();
    if (tid == 0) {
        int s = 0;
        #pragma unroll
        for (int k = 0; k < CNODES / 64; k++) { int t = wpre2[k]; wpre2[k] = s; s += t; }
    }
    __syncthreads();
    if (tid < CNODES) {
        int ex = wpre2[wid] + v - c;
        beg2[tid] = ex;
        cur[tid]  = ex;
        int node = rowB + tid;
        if (node < N) off[node] = cbeg + ex;     // for aggep3
    }
    __syncthreads();

    // ---- scatter sorted src ids to global ssrc ----
    for (int i = tid; i < ec; i += 512) {
        int p = pe[i];
        int pos = cbeg + atomicAdd(&cur[(p >> 17) & (CNODES - 1)], 1);
        ssrc[pos] = p & 0x1FFFF;
    }
    __syncthreads();

    // ---- gather: wave w owns rows w*32..w*32+31 (4 passes x 8 rows) ----
    const int w = wid;
    const int q = (lane & 7) * 8;
    #pragma unroll
    for (int pass = 0; pass < 4; pass++) {
        int rl = w * 32 + pass * 8 + (lane >> 3);
        int g  = rowB + rl;
        uint4 p = make_uint4(0u, 0u, 0u, 0u);
        if (g < N) {
            int beg = cbeg + beg2[rl];
            int end = beg + cnt[rl];
            p = gather_row(featbf, ssrc, beg, end, q);
        }
        *(uint4*)(Agg + rl * 72 + q) = p;
    }
    // Agg rows wave-local -> no barrier needed (in-wave lgkmcnt ordering)

    // ---- GEMM1 + sigmoid for 2 sub-tiles (16 rows each) per wave ----
    const int m = lane & 15, quad = lane >> 4;
    const short8* Wf = (const short8*)(img + W1F_OFF);
    #pragma unroll
    for (int sub = 0; sub < 2; sub++) {
        const int r0l = w * 32 + sub * 16;
        floatx4 acc[4];
        #pragma unroll
        for (int cc = 0; cc < 4; cc++) acc[cc] = (floatx4){0.f, 0.f, 0.f, 0.f};
        #pragma unroll
        for (int kk = 0; kk < 2; kk++) {
            short8 a = *(const short8*)(Agg + (r0l + m) * 72 + kk * 32 + quad * 8);
            #pragma unroll
            for (int cc = 0; cc < 4; cc++) {
                short8 b = Wf[((cc * 2 + kk) * 4 + quad) * 16 + m];
                acc[cc] = __builtin_amdgcn_mfma_f32_16x16x32_bf16(a, b, acc[cc], 0, 0, 0);
            }
        }
        bool dzr[4];
        int rows[4];
        #pragma unroll
        for (int r = 0; r < 4; r++) {
            int rl = r0l + quad * 4 + r;
            rows[r] = rowB + rl;
            dzr[r] = (cnt[rl] == 0);
        }
        #pragma unroll
        for (int cc = 0; cc < 4; cc++) {
            int col = cc * 16 + m;
            float bv = bias[col];
            #pragma unroll
            for (int r = 0; r < 4; r++) {
                if (rows[r] < N) {
                    float vv = dzr[r] ? 0.5f : sigmoidf(acc[cc][r] + bv);
                    t1[(size_t)rows[r] * 64 + col] = f2bf(vv);
                }
            }
        }
    }
}

// ---------------- wave-local gather wrapper for aggep3 (R21 form) ----------
__device__ __forceinline__ void gather_tile_wave(
    const unsigned short* __restrict__ h, const int* __restrict__ off,
    const int* __restrict__ ssrc, unsigned short* Agg, int rowB, int N,
    int w, int lane)
{
    #pragma unroll
    for (int pass = 0; pass < 2; pass++) {
        int rl = w * 16 + pass * 8 + (lane >> 3);
        int g  = rowB + rl;
        int q  = (lane & 7) * 8;
        uint4 p = make_uint4(0u, 0u, 0u, 0u);
        if (g < N) {
            p = gather_row(h, ssrc, off[g], off[g + 1], q);
        }
        *(uint4*)(Agg + rl * 72 + q) = p;
    }
}

// ---------------- fused gather + triple-GEMM -> out (R21 verbatim) ---------
// 128 threads / 32-row tile; LDS: T2[0,2304) | Agg/H3h[2304,4608) shorts.
__global__ __launch_bounds__(128) void aggep3_k(
    const unsigned short* __restrict__ t1, const int* __restrict__ off,
    const int* __restrict__ ssrc, const unsigned short* __restrict__ img,
    const float* __restrict__ b2, const float* __restrict__ b3,
    const float* __restrict__ b4, float* __restrict__ out, int N)
{
    __shared__ alignas(16) unsigned short SM[4608];   // 9.2 KB
    unsigned short* T2  = SM;            // 32 x 72
    unsigned short* Agg = SM + 2304;     // 32 x 72 (dead after phase 0)
    unsigned short* H3h = SM + 2304;     // aliases Agg

    const int tid = threadIdx.x;
    const int rowB = blockIdx.x * 32;
    const int w = tid >> 6, lane = tid & 63;
    const int m = lane & 15, quad = lane >> 4;
    const int row0 = rowB + w * 16;

    gather_tile_wave(t1, off, ssrc, Agg, rowB, N, w, lane);

    // ---- phase 0: T2 = sigmoid(Agg @ W2 + b2) ----
    {
        const short8* Wf = (const short8*)(img + W2F_OFF);
        floatx4 acc[4];
        #pragma unroll
        for (int c = 0; c < 4; c++) acc[c] = (floatx4){0.f, 0.f, 0.f, 0.f};
        #pragma unroll
        for (int kk = 0; kk < 2; kk++) {
            short8 a = *(const short8*)(Agg + (w * 16 + m) * 72 + kk * 32 + quad * 8);
            #pragma unroll
            for (int c = 0; c < 4; c++) {
                short8 b = Wf[((c * 2 + kk) * 4 + quad) * 16 + m];
                acc[c] = __builtin_amdgcn_mfma_f32_16x16x32_bf16(a, b, acc[c], 0, 0, 0);
            }
        }
        bool dzr[4];
        #pragma unroll
        for (int r = 0; r < 4; r++) {
            int row = row0 + quad * 4 + r;
            dzr[r] = (row < N) ? (off[row + 1] == off[row]) : false;
        }
        #pragma unroll
        for (int c = 0; c < 4; c++) {
            int col = c * 16 + m;
            float bv = b2[col];
            #pragma unroll
            for (int r = 0; r < 4; r++) {
                int rl = w * 16 + quad * 4 + r;
                float v = dzr[r] ? 0.5f : sigmoidf(acc[c][r] + bv);
                T2[rl * 72 + col] = f2bf(v);
            }
        }
    }

    // ---- phases 1&2 split-K: per half, H3h = relu(T2@W3half+b3half),
    //      then acc2 += H3h @ W4[khalf] ----
    floatx4 acc2[3];
    #pragma unroll
    for (int c = 0; c < 3; c++) acc2[c] = (floatx4){0.f, 0.f, 0.f, 0.f};
    const short8* Wf3 = (const short8*)(img + W3F_OFF);
    const short8* Wf4 = (const short8*)(img + W4F_OFF);

    #pragma unroll
    for (int half = 0; half < 2; half++) {
        floatx4 acc[4];
        #pragma unroll
        for (int c = 0; c < 4; c++) acc[c] = (floatx4){0.f, 0.f, 0.f, 0.f};
        #pragma unroll
        for (int kk = 0; kk < 2; kk++) {
            short8 a = *(const short8*)(T2 + (w * 16 + m) * 72 + kk * 32 + quad * 8);
            #pragma unroll
            for (int c = 0; c < 4; c++) {
                short8 b = Wf3[(((half * 4 + c) * 2 + kk) * 4 + quad) * 16 + m];
                acc[c] = __builtin_amdgcn_mfma_f32_16x16x32_bf16(a, b, acc[c], 0, 0, 0);
            }
        }
        #pragma unroll
        for (int c = 0; c < 4; c++) {
            int col = c * 16 + m;
            float bv = b3[half * 64 + col];
            #pragma unroll
            for (int r = 0; r < 4; r++) {
                int rl = w * 16 + quad * 4 + r;
                H3h[rl * 72 + col] = f2bf(fmaxf(acc[c][r] + bv, 0.f));
            }
        }
        #pragma unroll
        for (int kk2 = 0; kk2 < 2; kk2++) {
            short8 a = *(const short8*)(H3h + (w * 16 + m) * 72 + kk2 * 32 + quad * 8);
            #pragma unroll
            for (int c = 0; c < 3; c++) {
                short8 b = Wf4[((c * 4 + half * 2 + kk2) * 4 + quad) * 16 + m];
                acc2[c] = __builtin_amdgcn_mfma_f32_16x16x32_bf16(a, b, acc2[c], 0, 0, 0);
            }
        }
    }

    // ---- store out = acc2 + b4 ----
    #pragma unroll
    for (int c = 0; c < 3; c++) {
        int col = c * 16 + m;
        if (col < 40) {
            float bv = b4[col];
            #pragma unroll
            for (int r = 0; r < 4; r++) {
                int row = row0 + quad * 4 + r;
                if (row < N) out[(size_t)row * 40 + col] = acc2[c][r] + bv;
            }
        }
    }
}

extern "C" void kernel_launch(void* const* d_in, const int* in_sizes, int n_in,
                              void* d_out, int out_size, void* d_ws, size_t ws_size,
                              hipStream_t stream)
{
    const float* feat = (const float*)d_in[0];
    const int*   eidx = (const int*)d_in[1];
    const float* W1 = (const float*)d_in[2];
    const float* b1 = (const float*)d_in[3];
    const float* W2 = (const float*)d_in[4];
    const float* b2 = (const float*)d_in[5];
    const float* W3 = (const float*)d_in[6];
    const float* b3 = (const float*)d_in[7];
    const float* W4 = (const float*)d_in[8];
    const float* b4 = (const float*)d_in[9];

    const int N = in_sizes[0] / 64;
    const int E = in_sizes[1] / 2;
    const int* src = eidx;
    const int* dst = eidx + E;

    const int NBUCK = (N + CNODES - 1) / CNODES;   // 391

    unsigned short* featbf = (unsigned short*)d_ws;            // N*64 bf16
    unsigned short* t1     = featbf + (size_t)N * 64;          // N*64 bf16
    unsigned short* img    = t1     + (size_t)N * 64;          // WIMG_TOT
    int*   off   = (int*)(img + WIMG_TOT);                     // N+1
    int*   ccur  = off + (N + 1);                              // NBUCK
    int*   ssrc  = ccur + NBUCK;                               // E
    int*   arena = ssrc + E;                                   // NBUCK*CAP
    float* out   = (float*)d_out;

    hipMemsetAsync(ccur, 0, (size_t)NBUCK * sizeof(int), stream);

    const int gP  = (E + EPB - 1) / EPB;           // 391
    const int n8  = N * 64 / 8;
    const int g32 = (N + 31) / 32;
    const int gPC = (n8 + WIMG_TOT + PTHR - 1) / PTHR;

    // CSR partition + prep (merged, 512thr, 1-atomic radix)  [R27]
    part_prep_k<<<gP + gPC, dim3(PTHR), 0, stream>>>(src, dst, ccur, arena, E,
                                                     NBUCK, gP, feat, featbf,
                                                     W1, W2, W3, W4, img, n8);

    // fused: per-bucket sort (writes off/ssrc) + gather + GEMM1 -> t1  [R26]
    aggemm1s_k<<<NBUCK, dim3(512), 0, stream>>>(featbf, ccur, arena, off, ssrc,
                                                img, b1, t1, N, E, NBUCK);

    // out = relu(sigmoid(mean(t1[src])@W2+b2)@W3+b3)@W4 + b4  [R21 verbatim]
    aggep3_k<<<g32, dim3(128), 0, stream>>>(t1, off, ssrc, img, b2, b3, b4, out, N);
}